// Round 4
// baseline (1052.127 us; speedup 1.0000x reference)
//
#include <hip/hip_runtime.h>
#include <hip/hip_bf16.h>

#define NROWS 128           // B*E rows
#define NCOLS 4096          // N
#define KVAL  64
#define NEGV  (-1e30f)

// ESP tables, j=0 column (identically 0) NOT stored: slot j-1 holds state j.
// Layout: [m][t][64], t in [0,4096]. 128 * 4097 * 64 * 4B = 134 MB each.
__device__ float g_suf[(size_t)NROWS * (NCOLS + 1) * 64];
__device__ float g_pre[(size_t)NROWS * (NCOLS + 1) * 64];
__device__ float g_th [(size_t)NROWS * NCOLS];                     // theta transposed: [m][t]
__device__ unsigned long long g_mask[(size_t)2 * NROWS * NCOLS];   // [e][m][t] ballot masks

// wave-wide shift-up-by-1 via DPP wave_shr:1 (0x138); lane 0 -> 0.0f.
__device__ __forceinline__ float wave_shr1_zero(float x) {
    int r = __builtin_amdgcn_update_dpp(0, __float_as_int(x), 0x138, 0xF, 0xF, true);
    return __int_as_float(r);
}

// fast logaddexp: max(a,b) + ln2 * log2(1 + exp2(-|a-b|*log2e))
__device__ __forceinline__ float lae_fast(float a, float b) {
    float mx = fmaxf(a, b);
    float d  = fabsf(a - b);
    float e  = __builtin_amdgcn_exp2f(d * -1.4426950408889634f);
    float lg = __builtin_amdgcn_logf(1.0f + e);
    return fmaf(lg, 0.6931471805599453f, mx);
}

// scores (64,4096,2) -> g_th[m=2b+e][t]
__global__ void transpose_kernel(const float* __restrict__ scores) {
    int idx = blockIdx.x * blockDim.x + threadIdx.x;   // over 64*4096
    int b = idx >> 12, n = idx & (NCOLS - 1);
    float2 v = ((const float2*)scores)[idx];
    g_th[(size_t)(2 * b)     * NCOLS + n] = v.x;
    g_th[(size_t)(2 * b + 1) * NCOLS + n] = v.y;
}

// One wave per DP chain. blocks [0,128): suffix (backward) + fused sampler-mask
// generation for both ensembles. [128,256): prefix (forward), pure.
// Lane l holds carry state j=l+1; state j=0 is identically 0 (DPP zero-fill).
__global__ __launch_bounds__(64) void dp_kernel(const float* __restrict__ u) {
    int blk = blockIdx.x;
    int l = threadIdx.x;
    bool suf = (blk < NROWS);
    int m = suf ? blk : (blk - NROWS);
    float* __restrict__ tab = (suf ? g_suf : g_pre) + (size_t)m * (NCOLS + 1) * 64;
    const float* __restrict__ th = g_th + (size_t)m * NCOLS;

    tab[(size_t)(suf ? NCOLS : 0) * 64 + l] = NEGV;    // init state row
    float s = NEGV;
    if (suf) {
        const float* __restrict__ u0 = u + (size_t)m * NCOLS;             // ens 0
        const float* __restrict__ u1 = u + (size_t)(NROWS + m) * NCOLS;   // ens 1
        unsigned long long* __restrict__ mk0 = g_mask + (size_t)m * NCOLS;
        unsigned long long* __restrict__ mk1 = g_mask + (size_t)(NROWS + m) * NCOLS;
        unsigned long long acc0 = 0, acc1 = 0;     // lane ss holds masks of step t0+ss
        for (int t0 = NCOLS - 64; t0 >= 0; t0 -= 64) {
            #pragma unroll 16
            for (int ss = 63; ss >= 0; --ss) {
                int t = t0 + ss;
                float tht = th[t];                  // uniform -> scalar load
                float sold = s;                     // row t+1 (state l+1)
                float num = wave_shr1_zero(sold);   // row t+1, state l (lane0 -> 0)
                float b = num + tht;
                s = lae_fast(sold, b);              // row t (state l+1) = den for r=l+1
                // sampler prob for r=l+1, same expression as the passing kernel
                float x = (tht + num) - s;
                float p = __builtin_amdgcn_exp2f(x * 1.4426950408889634f);
                unsigned long long b0 = __ballot(u0[t] < p);
                unsigned long long b1 = __ballot(u1[t] < p);
                if (l == ss) { acc0 = b0; acc1 = b1; }
                tab[(size_t)t * 64 + l] = s;
            }
            mk0[t0 + l] = acc0;                     // coalesced 512B per ensemble
            mk1[t0 + l] = acc1;
        }
    } else {
        #pragma unroll 8
        for (int t = 0; t < NCOLS; ++t) {
            float b = wave_shr1_zero(s) + th[t];
            s = lae_fast(s, b);
            tab[(size_t)(t + 1) * 64 + l] = s;
        }
    }
}

// ---- sampler scan: pure SALU walk over precomputed ballot masks ----
__device__ __forceinline__ void scan_body(int chain, int l, float* __restrict__ out) {
    int tens = chain >> 7;
    int m = chain & (NROWS - 1);
    const unsigned long long* __restrict__ gm =
        g_mask + ((size_t)tens * NROWS + m) * NCOLS;
    float* __restrict__ orow = out + (((size_t)tens * 64 + (m >> 1)) * NCOLS) * 2 + (m & 1);

    int r = KVAL;
    for (int t0 = 0; t0 < NCOLS; t0 += 64) {
        unsigned long long bits = 0ULL;
        #pragma unroll 16
        for (int ss = 0; ss < 64; ++ss) {
            unsigned long long mask = gm[t0 + ss];          // uniform -> s_load
            int inc = (r > 0) ? (int)((mask >> (r - 1)) & 1ULL) : 0;
            bits |= ((unsigned long long)inc) << ss;
            r -= inc;
        }
        orow[(size_t)(t0 + l) * 2] = (float)((bits >> l) & 1ULL);
    }
}

// ---- marginals: one wave per output element; lane l holds conv term a = l ----
__device__ __forceinline__ void marg_body(int w, int l, float* __restrict__ out) {
    int m = w >> 12;
    int i = w & (NCOLS - 1);
    size_t rowbase = (size_t)m * (NCOLS + 1) * 64;
    float vP = (l == 0)  ? 0.0f : g_pre[rowbase + (size_t)i * 64 + (l - 1)];
    float vS = (l == 63) ? 0.0f : g_suf[rowbase + (size_t)(i + 1) * 64 + (62 - l)];
    float v = vP + vS;
    float M = v;
    #pragma unroll
    for (int off = 32; off; off >>= 1) M = fmaxf(M, __shfl_xor(M, off));
    float e = expf(v - M);
    float sum = e;
    #pragma unroll
    for (int off = 32; off; off >>= 1) sum += __shfl_xor(sum, off);
    if (l == 0) {
        float lse = M + logf(sum);
        float den = g_pre[rowbase + (size_t)NCOLS * 64 + 63];   // log E_k(full row)
        float th  = g_th[(size_t)m * NCOLS + i];
        size_t obase = (size_t)2 * 64 * NCOLS * 2;
        out[obase + ((size_t)(m >> 1) * NCOLS + i) * 2 + (m & 1)] = expf(th + lse - den);
    }
}

#define SCAN_BLOCKS 64
#define MARG_BLOCKS ((NROWS * NCOLS) / 4)    // 4 waves per 256-thread block

__global__ __launch_bounds__(256) void tail_kernel(float* __restrict__ out) {
    int l = threadIdx.x & 63;
    int wib = threadIdx.x >> 6;
    if (blockIdx.x < SCAN_BLOCKS) {
        scan_body(blockIdx.x * 4 + wib, l, out);
    } else {
        marg_body((blockIdx.x - SCAN_BLOCKS) * 4 + wib, l, out);
    }
}

extern "C" void kernel_launch(void* const* d_in, const int* in_sizes, int n_in,
                              void* d_out, int out_size, void* d_ws, size_t ws_size,
                              hipStream_t stream) {
    const float* scores = (const float*)d_in[0];   // (64, 4096, 2) f32
    const float* u      = (const float*)d_in[1];   // (2, 128, 4096) f32
    float* out = (float*)d_out;

    transpose_kernel<<<(64 * NCOLS) / 256, 256, 0, stream>>>(scores);
    dp_kernel<<<2 * NROWS, 64, 0, stream>>>(u);
    tail_kernel<<<SCAN_BLOCKS + MARG_BLOCKS, 256, 0, stream>>>(out);
}

// Round 5
// 948.203 us; speedup vs baseline: 1.1096x; 1.1096x over previous
//
#include <hip/hip_runtime.h>
#include <hip/hip_bf16.h>

#define NROWS 128           // B*E rows
#define NCOLS 4096          // N
#define KVAL  64
#define NEGV  (-1e30f)
#define LOG2E 1.4426950408889634f
#define LN2   0.6931471805599453f

// ESP tables, j=0 column (identically 0) NOT stored: slot j-1 holds state j.
__device__ float g_suf[(size_t)NROWS * (NCOLS + 1) * 64];
__device__ float g_pre[(size_t)NROWS * (NCOLS + 1) * 64];
__device__ float g_th [(size_t)NROWS * NCOLS];                     // theta: [m][t]
__device__ unsigned long long g_mask[(size_t)2 * NROWS * NCOLS];   // [e][m][t]

// wave-wide shift-up-by-1 via DPP wave_shr:1 (0x138); lane 0 -> 0.0f.
__device__ __forceinline__ float wave_shr1_zero(float x) {
    int r = __builtin_amdgcn_update_dpp(0, __float_as_int(x), 0x138, 0xF, 0xF, true);
    return __int_as_float(r);
}

__device__ __forceinline__ float readlane_f(float v, int lane) {
    return __int_as_float(__builtin_amdgcn_readlane(__float_as_int(v), lane));
}

// fast logaddexp: max(a,b) + ln2 * log2(1 + exp2(-|a-b|*log2e))
__device__ __forceinline__ float lae_fast(float a, float b) {
    float mx = fmaxf(a, b);
    float d  = fabsf(a - b);
    float e  = __builtin_amdgcn_exp2f(d * -LOG2E);
    float lg = __builtin_amdgcn_logf(1.0f + e);
    return fmaf(lg, LN2, mx);
}

// scores (64,4096,2) -> g_th[m=2b+e][t]
__global__ void transpose_kernel(const float* __restrict__ scores) {
    int idx = blockIdx.x * blockDim.x + threadIdx.x;   // over 64*4096
    int b = idx >> 12, n = idx & (NCOLS - 1);
    float2 v = ((const float2*)scores)[idx];
    g_th[(size_t)(2 * b)     * NCOLS + n] = v.x;
    g_th[(size_t)(2 * b + 1) * NCOLS + n] = v.y;
}

// One wave per DP chain. blocks [0,128): suffix (backward) + fused sampler-mask
// generation (u fed from register tiles + v_readlane; nothing on the chain).
// blocks [128,256): prefix (forward), pure.
__global__ __launch_bounds__(64) void dp_kernel(const float* __restrict__ u) {
    int blk = blockIdx.x;
    int l = threadIdx.x;
    bool suf = (blk < NROWS);
    int m = suf ? blk : (blk - NROWS);
    float* __restrict__ tab = (suf ? g_suf : g_pre) + (size_t)m * (NCOLS + 1) * 64;
    const float* __restrict__ th = g_th + (size_t)m * NCOLS;

    tab[(size_t)(suf ? NCOLS : 0) * 64 + l] = NEGV;    // init state row
    float s = NEGV;
    if (suf) {
        const float* __restrict__ u0 = u + (size_t)m * NCOLS;             // ens 0
        const float* __restrict__ u1 = u + (size_t)(NROWS + m) * NCOLS;   // ens 1
        unsigned long long* __restrict__ mk0 = g_mask + (size_t)m * NCOLS;
        unsigned long long* __restrict__ mk1 = g_mask + (size_t)(NROWS + m) * NCOLS;
        for (int t0 = NCOLS - 64; t0 >= 0; t0 -= 64) {
            float u0t = u0[t0 + l];                     // coalesced 256B tiles
            float u1t = u1[t0 + l];
            unsigned long long acc0 = 0, acc1 = 0;      // lane ss <- masks of step t0+ss
            #pragma unroll 16
            for (int ss = 63; ss >= 0; --ss) {
                int t = t0 + ss;
                float tht = th[t];                      // uniform -> scalar load
                float num = wave_shr1_zero(s);          // row t+1, state l (lane0 -> 0)
                float b = num + tht;
                s = lae_fast(s, b);                     // row t, state l+1 (= den, r=l+1)
                float p = __builtin_amdgcn_exp2f((b - s) * LOG2E);   // exp((th+num)-den)
                float su0 = readlane_f(u0t, ss);
                float su1 = readlane_f(u1t, ss);
                unsigned long long b0 = __ballot(su0 < p);
                unsigned long long b1 = __ballot(su1 < p);
                acc0 = (l == ss) ? b0 : acc0;
                acc1 = (l == ss) ? b1 : acc1;
                tab[(size_t)t * 64 + l] = s;
            }
            mk0[t0 + l] = acc0;                         // coalesced 512B per ensemble
            mk1[t0 + l] = acc1;
        }
    } else {
        #pragma unroll 8
        for (int t = 0; t < NCOLS; ++t) {
            float b = wave_shr1_zero(s) + th[t];
            s = lae_fast(s, b);
            tab[(size_t)(t + 1) * 64 + l] = s;
        }
    }
}

// ---- sampler scan: pure SALU walk over precomputed ballot masks ----
__device__ __forceinline__ void scan_body(int chain, int l, float* __restrict__ out) {
    int tens = chain >> 7;
    int m = chain & (NROWS - 1);
    const unsigned long long* __restrict__ gm =
        g_mask + ((size_t)tens * NROWS + m) * NCOLS;
    float* __restrict__ orow = out + (((size_t)tens * 64 + (m >> 1)) * NCOLS) * 2 + (m & 1);

    int r = KVAL;
    for (int t0 = 0; t0 < NCOLS; t0 += 64) {
        unsigned long long bits = 0ULL;
        #pragma unroll 16
        for (int ss = 0; ss < 64; ++ss) {
            unsigned long long mask = gm[t0 + ss];          // uniform load
            int inc = (r > 0) ? (int)((mask >> (r - 1)) & 1ULL) : 0;
            bits |= ((unsigned long long)inc) << ss;
            r -= inc;
        }
        orow[(size_t)(t0 + l) * 2] = (float)((bits >> l) & 1ULL);
    }
}

// ---- marginals: ONE THREAD per element; reduction fully in-thread (no DS).
// v_a = P[i][a] + S[i+1][63-a]; slots: P a-1 (a=0 -> 0), S 62-a (a=63 -> 0).
__device__ __forceinline__ void marg_thread(int w, float* __restrict__ out) {
    int m = w >> 12;
    int i = w & (NCOLS - 1);
    size_t rowbase = (size_t)m * (NCOLS + 1) * 64;
    const float4* __restrict__ P4 = (const float4*)(g_pre + rowbase + (size_t)i * 64);
    const float4* __restrict__ S4 = (const float4*)(g_suf + rowbase + (size_t)(i + 1) * 64);

    float p[64], sfx[64];
    #pragma unroll
    for (int j = 0; j < 16; ++j) *(float4*)(p + 4 * j) = P4[j];
    #pragma unroll
    for (int j = 0; j < 16; ++j) *(float4*)(sfx + 4 * j) = S4[j];

    // pass 1: max
    float M = sfx[62];                       // a = 0
    M = fmaxf(M, p[62]);                     // a = 63
    #pragma unroll
    for (int a = 1; a < 63; ++a) M = fmaxf(M, p[a - 1] + sfx[62 - a]);
    // pass 2: sum of exp2
    float sum = __builtin_amdgcn_exp2f((sfx[62] - M) * LOG2E)
              + __builtin_amdgcn_exp2f((p[62]  - M) * LOG2E);
    #pragma unroll
    for (int a = 1; a < 63; ++a)
        sum += __builtin_amdgcn_exp2f((p[a - 1] + sfx[62 - a] - M) * LOG2E);

    float lse = fmaf(__builtin_amdgcn_logf(sum), LN2, M);
    float den = g_pre[rowbase + (size_t)NCOLS * 64 + 63];   // log E_k(full row)
    float th  = g_th[(size_t)m * NCOLS + i];
    float marg = __builtin_amdgcn_exp2f((th + lse - den) * LOG2E);

    size_t obase = (size_t)2 * 64 * NCOLS * 2;
    out[obase + ((size_t)(m >> 1) * NCOLS + i) * 2 + (m & 1)] = marg;
}

#define SCAN_BLOCKS 64
#define MARG_BLOCKS ((NROWS * NCOLS) / 256)    // one thread per element

__global__ __launch_bounds__(256, 2) void tail_kernel(float* __restrict__ out) {
    if (blockIdx.x < SCAN_BLOCKS) {
        int l = threadIdx.x & 63;
        int wib = threadIdx.x >> 6;
        scan_body(blockIdx.x * 4 + wib, l, out);
    } else {
        marg_thread((blockIdx.x - SCAN_BLOCKS) * 256 + threadIdx.x, out);
    }
}

extern "C" void kernel_launch(void* const* d_in, const int* in_sizes, int n_in,
                              void* d_out, int out_size, void* d_ws, size_t ws_size,
                              hipStream_t stream) {
    const float* scores = (const float*)d_in[0];   // (64, 4096, 2) f32
    const float* u      = (const float*)d_in[1];   // (2, 128, 4096) f32
    float* out = (float*)d_out;

    transpose_kernel<<<(64 * NCOLS) / 256, 256, 0, stream>>>(scores);
    dp_kernel<<<2 * NROWS, 64, 0, stream>>>(u);
    tail_kernel<<<SCAN_BLOCKS + MARG_BLOCKS, 256, 0, stream>>>(out);
}

// Round 6
// 500.166 us; speedup vs baseline: 2.1036x; 1.8958x over previous
//
#include <hip/hip_runtime.h>
#include <hip/hip_bf16.h>

#define NROWS 128           // B*E rows
#define NCOLS 4096          // N
#define KVAL  64
#define NEGV  (-1e30f)
#define LOG2E 1.4426950408889634f
#define LN2   0.6931471805599453f

// ESP tables, j=0 column (identically 0) NOT stored: slot j-1 holds state j.
__device__ float g_suf[(size_t)NROWS * (NCOLS + 1) * 64];
__device__ float g_pre[(size_t)NROWS * (NCOLS + 1) * 64];
__device__ float g_th [(size_t)NROWS * NCOLS];                     // theta: [m][t]
__device__ unsigned long long g_mask[(size_t)2 * NROWS * NCOLS];   // [e][m][t]

// wave-wide shift-up-by-1 via DPP wave_shr:1 (0x138); lane 0 -> 0.0f.
__device__ __forceinline__ float wave_shr1_zero(float x) {
    int r = __builtin_amdgcn_update_dpp(0, __float_as_int(x), 0x138, 0xF, 0xF, true);
    return __int_as_float(r);
}

// fast logaddexp: max(a,b) + ln2 * log2(1 + exp2(-|a-b|*log2e))
__device__ __forceinline__ float lae_fast(float a, float b) {
    float mx = fmaxf(a, b);
    float d  = fabsf(a - b);
    float e  = __builtin_amdgcn_exp2f(d * -LOG2E);
    float lg = __builtin_amdgcn_logf(1.0f + e);
    return fmaf(lg, LN2, mx);
}

// scores (64,4096,2) -> g_th[m=2b+e][t]
__global__ void transpose_kernel(const float* __restrict__ scores) {
    int idx = blockIdx.x * blockDim.x + threadIdx.x;   // over 64*4096
    int b = idx >> 12, n = idx & (NCOLS - 1);
    float2 v = ((const float2*)scores)[idx];
    g_th[(size_t)(2 * b)     * NCOLS + n] = v.x;
    g_th[(size_t)(2 * b + 1) * NCOLS + n] = v.y;
}

// Pure DP (round-3 form, known-fast). One wave per chain; blocks [0,128):
// suffix (backward), [128,256): prefix (forward). Lane l = state j=l+1.
__global__ __launch_bounds__(64) void dp_kernel() {
    int blk = blockIdx.x;
    int l = threadIdx.x;
    bool suf = (blk < NROWS);
    int m = suf ? blk : (blk - NROWS);
    float* __restrict__ tab = (suf ? g_suf : g_pre) + (size_t)m * (NCOLS + 1) * 64;
    const float* __restrict__ th = g_th + (size_t)m * NCOLS;

    tab[(size_t)(suf ? NCOLS : 0) * 64 + l] = NEGV;    // init state row
    float s = NEGV;
    if (suf) {
        #pragma unroll 8
        for (int tt = 0; tt < NCOLS; ++tt) {
            int t = NCOLS - 1 - tt;
            float b = wave_shr1_zero(s) + th[t];       // th[t] uniform -> s_load
            s = lae_fast(s, b);
            tab[(size_t)t * 64 + l] = s;
        }
    } else {
        #pragma unroll 8
        for (int t = 0; t < NCOLS; ++t) {
            float b = wave_shr1_zero(s) + th[t];
            s = lae_fast(s, b);
            tab[(size_t)(t + 1) * 64 + l] = s;
        }
    }
}

// ---- marginals: one wave per element (coalesced row loads + shfl reduce) ----
__device__ __forceinline__ void marg_body(int w, int l, float* __restrict__ out) {
    int m = w >> 12;
    int i = w & (NCOLS - 1);
    size_t rowbase = (size_t)m * (NCOLS + 1) * 64;
    float vP = (l == 0)  ? 0.0f : g_pre[rowbase + (size_t)i * 64 + (l - 1)];
    float vS = (l == 63) ? 0.0f : g_suf[rowbase + (size_t)(i + 1) * 64 + (62 - l)];
    float v = vP + vS;
    float M = v;
    #pragma unroll
    for (int off = 32; off; off >>= 1) M = fmaxf(M, __shfl_xor(M, off));
    float e = expf(v - M);
    float sum = e;
    #pragma unroll
    for (int off = 32; off; off >>= 1) sum += __shfl_xor(sum, off);
    if (l == 0) {
        float lse = M + logf(sum);
        float den = g_pre[rowbase + (size_t)NCOLS * 64 + 63];   // log E_k(full row)
        float th  = g_th[(size_t)m * NCOLS + i];
        size_t obase = (size_t)2 * 64 * NCOLS * 2;
        out[obase + ((size_t)(m >> 1) * NCOLS + i) * 2 + (m & 1)] = expf(th + lse - den);
    }
}

// ---- mask gen (parallel, 8192 waves) + marg fused in one launch ----
#define MASK_BLOCKS 2048                   // 8192 units: (m, t-block of 64)
#define MARG_BLOCKS 8192                   // 32768 waves x 16 elements

__global__ __launch_bounds__(256) void mid_kernel(const float* __restrict__ u,
                                                  float* __restrict__ out) {
    int l = threadIdx.x & 63;
    int wid = threadIdx.x >> 6;
    if (blockIdx.x < MASK_BLOCKS) {
        int unit = blockIdx.x * 4 + wid;
        int m  = unit >> 6;
        int t0 = (unit & 63) << 6;
        const float* __restrict__ S = g_suf + (size_t)m * (NCOLS + 1) * 64;
        const float* __restrict__ trow = g_th + (size_t)m * NCOLS;
        const float* __restrict__ u0 = u + (size_t)m * NCOLS;             // ens 0
        const float* __restrict__ u1 = u + (size_t)(NROWS + m) * NCOLS;   // ens 1

        float R[65];                       // rows t0..t0+64, lane l = state l+1
        #pragma unroll
        for (int j = 0; j < 65; ++j) R[j] = S[(size_t)(t0 + j) * 64 + l];

        unsigned long long acc0 = 0, acc1 = 0;   // lane ss <- masks of step t0+ss
        #pragma unroll
        for (int ss = 0; ss < 64; ++ss) {
            int t = t0 + ss;
            float num = wave_shr1_zero(R[ss + 1]);   // state l at row t+1 (lane0->0)
            float den = R[ss];                       // state l+1 at row t
            // identical expression to the passing fused version: exp((num+th)-den)
            float p = __builtin_amdgcn_exp2f(((num + trow[t]) - den) * LOG2E);
            unsigned long long b0 = __ballot(u0[t] < p);
            unsigned long long b1 = __ballot(u1[t] < p);
            acc0 = (l == ss) ? b0 : acc0;
            acc1 = (l == ss) ? b1 : acc1;
        }
        g_mask[(size_t)m * NCOLS + t0 + l] = acc0;               // coalesced 512B
        g_mask[(size_t)(NROWS + m) * NCOLS + t0 + l] = acc1;
    } else {
        int w = (blockIdx.x - MASK_BLOCKS) * 4 + wid;            // 16 elems per wave
        #pragma unroll 2
        for (int j = 0; j < 16; ++j) marg_body(w * 16 + j, l, out);
    }
}

// ---- sampler scan: register-tiled masks + __shfl broadcast (no mem on chain) ----
__global__ __launch_bounds__(64) void scan_kernel(float* __restrict__ out) {
    int chain = blockIdx.x;              // 0..255
    int l = threadIdx.x;
    int tens = chain >> 7;
    int m = chain & (NROWS - 1);
    const unsigned long long* __restrict__ gm =
        g_mask + ((size_t)tens * NROWS + m) * NCOLS;
    float* __restrict__ orow = out + (((size_t)tens * 64 + (m >> 1)) * NCOLS) * 2 + (m & 1);

    int r = KVAL;
    unsigned long long tile = gm[l];                 // coalesced 512B tile
    for (int t0 = 0; t0 < NCOLS; t0 += 64) {
        unsigned long long next = (t0 + 64 < NCOLS) ? gm[t0 + 64 + l] : 0ULL;
        int myinc = 0;
        #pragma unroll
        for (int ss = 0; ss < 64; ++ss) {
            unsigned long long msk = __shfl(tile, ss);           // VGPR broadcast
            int inc = (r > 0) ? (int)((msk >> (r - 1)) & 1ULL) : 0;
            myinc = (ss == l) ? inc : myinc;
            r -= inc;
        }
        orow[(size_t)(t0 + l) * 2] = (float)myinc;
        tile = next;
    }
}

extern "C" void kernel_launch(void* const* d_in, const int* in_sizes, int n_in,
                              void* d_out, int out_size, void* d_ws, size_t ws_size,
                              hipStream_t stream) {
    const float* scores = (const float*)d_in[0];   // (64, 4096, 2) f32
    const float* u      = (const float*)d_in[1];   // (2, 128, 4096) f32
    float* out = (float*)d_out;

    transpose_kernel<<<(64 * NCOLS) / 256, 256, 0, stream>>>(scores);
    dp_kernel<<<2 * NROWS, 64, 0, stream>>>();
    mid_kernel<<<MASK_BLOCKS + MARG_BLOCKS, 256, 0, stream>>>(u, out);
    scan_kernel<<<2 * NROWS, 64, 0, stream>>>(out);
}